// Round 16
// baseline (313.725 us; speedup 1.0000x reference)
//
#include <hip/hip_runtime.h>

// Affine_Linear_Abla_Quat — v11: two-pass decoupling.
// Six structural failures (v4,v5,v6,v8,v10) all tried to overlap the
// HBM-latency quat phase and the L2-latency GEMM phase INSIDE one block and
// paid for it (spill / VGPR starvation / L2 partial-line thrash). v11 splits:
//   Pass A: streaming quat->terms (bf16) -> d_ws. No LDS, no barriers.
//   Pass B: GEMM terms x W -> Y. A-frags from GLOBAL (no LDS, no barriers,
//           occupancy ~8 waves/SIMD, VGPR-bound only).
// Fallback to v3 fused if ws_size < 151.4 MB.

typedef __bf16 bf16_t;
typedef __attribute__((ext_vector_type(8))) __bf16 bf16x8;
typedef __attribute__((ext_vector_type(4))) __bf16 bf16x4;
typedef __attribute__((ext_vector_type(4))) float f32x4;

constexpr int Dd  = 256;   // D == F
constexpr int Gp  = 16;    // pairs per GEMM block -> M = 48
constexpr int TPB = 512;   // 8 waves

__device__ __forceinline__ bf16_t to_bf16(float f) {
    unsigned u = __builtin_bit_cast(unsigned, f);
    u += 0x7FFFu + ((u >> 16) & 1u);          // RNE
    unsigned short h = (unsigned short)(u >> 16);
    return __builtin_bit_cast(bf16_t, h);
}

__device__ __forceinline__ int swz(int row, int k) {
    return row * 768 + (k ^ ((row & 7) << 3));
}

// ---- prologue: A,B,C (f32 256x256) -> W bf16 [3][256][256] ----
__global__ __launch_bounds__(256)
void convert_w_kernel(const float* __restrict__ A, const float* __restrict__ B,
                      const float* __restrict__ C, bf16_t* __restrict__ W)
{
    const int e4 = (blockIdx.x * 256 + threadIdx.x) * 4;
    const float* src;
    if (e4 < 65536)        src = A + e4;
    else if (e4 < 131072)  src = B + (e4 - 65536);
    else                   src = C + (e4 - 131072);
    const float4 v = *reinterpret_cast<const float4*>(src);
    bf16x4 o;
    o[0] = to_bf16(v.x); o[1] = to_bf16(v.y); o[2] = to_bf16(v.z); o[3] = to_bf16(v.w);
    *reinterpret_cast<bf16x4*>(W + e4) = o;
}

// ---------------- Pass A: quat -> terms T[(pair*3+i)*768 + term*256 + e] ----------------
__global__ __launch_bounds__(256)
void terms_kernel(const float* __restrict__ X, const float* __restrict__ J,
                  bf16_t* __restrict__ T, int nelem)
{
    for (int idx = blockIdx.x * 256 + threadIdx.x; idx < nelem;
         idx += gridDim.x * 256) {
        const int p = idx >> 8;        // global pair
        const int e = idx & 255;

        const float4 q = *reinterpret_cast<const float4*>(J + (long)idx * 4);
        const float* xp = X + (long)idx * 3;
        const float x0 = xp[0], x1 = xp[1], x2 = xp[2];

        const float nsq = q.x*q.x + q.y*q.y + q.z*q.z + q.w*q.w;
        const float inv = 1.0f / fmaxf(sqrtf(nsq), 1e-12f);
        const float qx = q.x*inv, qy = q.y*inv, qz = q.z*inv, qw = q.w*inv;
        const float s = 2.0f / (qw*qw + qx*qx + qy*qy + qz*qz);

        const float r00 = 1.0f - s*(qy*qy + qz*qz);
        const float r01 = s*(qx*qy - qz*qw);
        const float r02 = s*(qx*qz + qy*qw);
        const float r10 = s*(qx*qy + qz*qw);
        const float r11 = 1.0f - s*(qx*qx + qz*qz);
        const float r12 = s*(qy*qz - qx*qw);
        const float r20 = s*(qx*qz - qy*qw);
        const float r21 = s*(qy*qz + qx*qw);
        const float r22 = 1.0f - s*(qx*qx + qy*qy);

        const float rt0 = r00*x0 + r10*x1 + r20*x2;
        const float rt1 = r01*x0 + r11*x1 + r21*x2;
        const float rt2 = r02*x0 + r12*x1 + r22*x2;

        bf16_t* t = T + (long)(p * 3) * 768 + e;
        t[0]              = to_bf16(r00*rt0 + r01*rt1);
        t[768]            = to_bf16(r10*rt0 + r11*rt1);
        t[1536]           = to_bf16(r20*rt0 + r21*rt1);
        t[256]            = to_bf16(r01*rt0 - r00*rt1);
        t[768 + 256]      = to_bf16(r11*rt0 - r10*rt1);
        t[1536 + 256]     = to_bf16(r21*rt0 - r20*rt1);
        t[512]            = to_bf16(r02*rt2);
        t[768 + 512]      = to_bf16(r12*rt2);
        t[1536 + 512]     = to_bf16(r22*rt2);
    }
}

// ---------------- Pass B: GEMM T x W -> Y (no LDS, no barriers) ----------------
__global__ __launch_bounds__(TPB)
void gemm_kernel(const bf16_t* __restrict__ T, const bf16_t* __restrict__ W,
                 float* __restrict__ Y)
{
    const int tid = threadIdx.x;
    const long bn0 = (long)blockIdx.x * Gp;

    const int w  = tid >> 6;
    const int l  = tid & 63;
    const int lr = l & 15;
    const int lq = l >> 4;

    f32x4 acc[3][2] = {};

    const bf16_t* Wf0 = W + ((2 * w) * 16 + lr) * 256 + (lq << 3);
    const bf16_t* Wf1 = Wf0 + 16 * 256;
    // A-frag rows: m_global = blk*48 + mi*16 + lr
    const bf16_t* Ta = T + (bn0 * 3 + lr) * 768 + (lq << 3);

    #pragma unroll
    for (int k0 = 0; k0 < 24; ++k0) {
        const int term = k0 >> 3;
        const int eb   = (k0 & 7) << 5;
        const bf16x8 b0 = *reinterpret_cast<const bf16x8*>(Wf0 + (term << 16) + eb);
        const bf16x8 b1 = *reinterpret_cast<const bf16x8*>(Wf1 + (term << 16) + eb);

        const int kof = k0 << 5;
        const bf16x8 a0 = *reinterpret_cast<const bf16x8*>(Ta              + kof);
        const bf16x8 a1 = *reinterpret_cast<const bf16x8*>(Ta + 16 * 768   + kof);
        const bf16x8 a2 = *reinterpret_cast<const bf16x8*>(Ta + 32 * 768   + kof);

        acc[0][0] = __builtin_amdgcn_mfma_f32_16x16x32_bf16(a0, b0, acc[0][0], 0, 0, 0);
        acc[1][0] = __builtin_amdgcn_mfma_f32_16x16x32_bf16(a1, b0, acc[1][0], 0, 0, 0);
        acc[2][0] = __builtin_amdgcn_mfma_f32_16x16x32_bf16(a2, b0, acc[2][0], 0, 0, 0);
        acc[0][1] = __builtin_amdgcn_mfma_f32_16x16x32_bf16(a0, b1, acc[0][1], 0, 0, 0);
        acc[1][1] = __builtin_amdgcn_mfma_f32_16x16x32_bf16(a1, b1, acc[1][1], 0, 0, 0);
        acc[2][1] = __builtin_amdgcn_mfma_f32_16x16x32_bf16(a2, b1, acc[2][1], 0, 0, 0);
    }

    #pragma unroll
    for (int mi = 0; mi < 3; ++mi) {
        #pragma unroll
        for (int ni = 0; ni < 2; ++ni) {
            const int f = (2 * w + ni) * 16 + lr;
            #pragma unroll
            for (int r = 0; r < 4; ++r) {
                const int m = mi * 16 + lq * 4 + r;
                const int p = m / 3;
                const int i = m - p * 3;
                Y[(bn0 + p) * 768 + f * 3 + i] = acc[mi][ni][r];
            }
        }
    }
}

// ---------------- Fallback: v3 fused (needs only W in d_ws) ----------------
__global__ __launch_bounds__(TPB, 4)
void alaq_fused_v3(const float* __restrict__ X, const float* __restrict__ J,
                   const bf16_t* __restrict__ W, float* __restrict__ Y)
{
    __shared__ bf16_t TT[48 * 768];
    const int tid = threadIdx.x;
    const long bn0 = (long)blockIdx.x * Gp;
    const long ebase = bn0 * Dd;

    #pragma unroll
    for (int rr = 0; rr < 8; ++rr) {
        const int idx = rr * TPB + tid;
        const int p = idx >> 8;
        const int e = idx & 255;
        const long base = ebase + idx;
        const float4 q = *reinterpret_cast<const float4*>(J + base * 4);
        const float* xp = X + base * 3;
        const float x0 = xp[0], x1 = xp[1], x2 = xp[2];
        const float nsq = q.x*q.x + q.y*q.y + q.z*q.z + q.w*q.w;
        const float inv = 1.0f / fmaxf(sqrtf(nsq), 1e-12f);
        const float qx = q.x*inv, qy = q.y*inv, qz = q.z*inv, qw = q.w*inv;
        const float s = 2.0f / (qw*qw + qx*qx + qy*qy + qz*qz);
        const float r00 = 1.0f - s*(qy*qy + qz*qz);
        const float r01 = s*(qx*qy - qz*qw);
        const float r02 = s*(qx*qz + qy*qw);
        const float r10 = s*(qx*qy + qz*qw);
        const float r11 = 1.0f - s*(qx*qx + qz*qz);
        const float r12 = s*(qy*qz - qx*qw);
        const float r20 = s*(qx*qz - qy*qw);
        const float r21 = s*(qy*qz + qx*qw);
        const float r22 = 1.0f - s*(qx*qx + qy*qy);
        const float rt0 = r00*x0 + r10*x1 + r20*x2;
        const float rt1 = r01*x0 + r11*x1 + r21*x2;
        const float rt2 = r02*x0 + r12*x1 + r22*x2;
        const int row = p * 3;
        TT[swz(row    ,       e)] = to_bf16(r00*rt0 + r01*rt1);
        TT[swz(row + 1,       e)] = to_bf16(r10*rt0 + r11*rt1);
        TT[swz(row + 2,       e)] = to_bf16(r20*rt0 + r21*rt1);
        TT[swz(row    , 256 + e)] = to_bf16(r01*rt0 - r00*rt1);
        TT[swz(row + 1, 256 + e)] = to_bf16(r11*rt0 - r10*rt1);
        TT[swz(row + 2, 256 + e)] = to_bf16(r21*rt0 - r20*rt1);
        TT[swz(row    , 512 + e)] = to_bf16(r02*rt2);
        TT[swz(row + 1, 512 + e)] = to_bf16(r12*rt2);
        TT[swz(row + 2, 512 + e)] = to_bf16(r22*rt2);
    }
    __syncthreads();

    const int w  = tid >> 6;
    const int l  = tid & 63;
    const int lr = l & 15;
    const int lq = l >> 4;
    f32x4 acc[3][2] = {};
    const bf16_t* Wf0 = W + ((2 * w) * 16 + lr) * 256 + (lq << 3);
    const bf16_t* Wf1 = Wf0 + 16 * 256;
    const int swzmask = (lr & 7) << 3;

    #pragma unroll
    for (int k0 = 0; k0 < 24; ++k0) {
        const int term = k0 >> 3;
        const int eb   = (k0 & 7) << 5;
        const bf16x8 b0 = *reinterpret_cast<const bf16x8*>(Wf0 + (term << 16) + eb);
        const bf16x8 b1 = *reinterpret_cast<const bf16x8*>(Wf1 + (term << 16) + eb);
        const int kswz = (((k0 << 5) + (lq << 3)) ^ swzmask);
        const bf16x8 a0 = *reinterpret_cast<const bf16x8*>(&TT[      lr  * 768 + kswz]);
        const bf16x8 a1 = *reinterpret_cast<const bf16x8*>(&TT[(16 + lr) * 768 + kswz]);
        const bf16x8 a2 = *reinterpret_cast<const bf16x8*>(&TT[(32 + lr) * 768 + kswz]);
        acc[0][0] = __builtin_amdgcn_mfma_f32_16x16x32_bf16(a0, b0, acc[0][0], 0, 0, 0);
        acc[1][0] = __builtin_amdgcn_mfma_f32_16x16x32_bf16(a1, b0, acc[1][0], 0, 0, 0);
        acc[2][0] = __builtin_amdgcn_mfma_f32_16x16x32_bf16(a2, b0, acc[2][0], 0, 0, 0);
        acc[0][1] = __builtin_amdgcn_mfma_f32_16x16x32_bf16(a0, b1, acc[0][1], 0, 0, 0);
        acc[1][1] = __builtin_amdgcn_mfma_f32_16x16x32_bf16(a1, b1, acc[1][1], 0, 0, 0);
        acc[2][1] = __builtin_amdgcn_mfma_f32_16x16x32_bf16(a2, b1, acc[2][1], 0, 0, 0);
    }

    #pragma unroll
    for (int mi = 0; mi < 3; ++mi) {
        #pragma unroll
        for (int ni = 0; ni < 2; ++ni) {
            const int f = (2 * w + ni) * 16 + lr;
            #pragma unroll
            for (int r = 0; r < 4; ++r) {
                const int m = mi * 16 + lq * 4 + r;
                const int p = m / 3;
                const int i = m - p * 3;
                Y[(bn0 + p) * 768 + f * 3 + i] = acc[mi][ni][r];
            }
        }
    }
}

extern "C" void kernel_launch(void* const* d_in, const int* in_sizes, int n_in,
                              void* d_out, int out_size, void* d_ws, size_t ws_size,
                              hipStream_t stream) {
    const float* X  = (const float*)d_in[0];
    const float* J  = (const float*)d_in[1];
    const float* A  = (const float*)d_in[2];
    const float* B  = (const float*)d_in[3];
    const float* Cm = (const float*)d_in[4];
    float* Y = (float*)d_out;

    bf16_t* W = (bf16_t*)d_ws;                       // 393,216 B
    const int nbn = in_sizes[1] / (Dd * 4);          // 32768
    const int nelem = nbn * Dd;                      // 8,388,608
    const size_t t_bytes = (size_t)nbn * 3 * 768 * sizeof(bf16_t);  // 150,994,944
    const size_t need = 393216 + t_bytes;

    convert_w_kernel<<<192, 256, 0, stream>>>(A, B, Cm, W);

    if (ws_size >= need) {
        bf16_t* T = (bf16_t*)((char*)d_ws + 393216);
        terms_kernel<<<2048, 256, 0, stream>>>(X, J, T, nelem);
        gemm_kernel<<<nbn / Gp, TPB, 0, stream>>>(T, W, Y);
    } else {
        alaq_fused_v3<<<nbn / Gp, TPB, 0, stream>>>(X, J, W, Y);
    }
}